// Round 1
// baseline (35.080 us; speedup 1.0000x reference)
//
#include <hip/hip_runtime.h>

// GroupSort: out[:, 2k]   = min(x[:, 2k], x[:, 2k+1])
//            out[:, 2k+1] = max(x[:, 2k], x[:, 2k+1])
// x: (32, 256, 56, 56) f32 contiguous. Plane = 56*56 = 3136 floats = 784 float4.
// Pair of planes = 1568 float4. Total pairs = 32*128 = 4096.
// Total pair-vectors = 4096 * 784 = 3,211,264.

#define HW4   784      // float4s per channel plane
#define PAIR4 1568     // float4s per channel pair (2 planes)

__global__ __launch_bounds__(256) void groupsort_kernel(const float4* __restrict__ x,
                                                        float4* __restrict__ out,
                                                        int total) {
    int i = blockIdx.x * 256 + threadIdx.x;
    if (i >= total) return;
    int pair = i / HW4;
    int pos  = i - pair * HW4;
    int base = pair * PAIR4 + pos;

    float4 a = x[base];          // even channel
    float4 b = x[base + HW4];    // odd channel

    float4 lo, hi;
    lo.x = fminf(a.x, b.x); hi.x = fmaxf(a.x, b.x);
    lo.y = fminf(a.y, b.y); hi.y = fmaxf(a.y, b.y);
    lo.z = fminf(a.z, b.z); hi.z = fmaxf(a.z, b.z);
    lo.w = fminf(a.w, b.w); hi.w = fmaxf(a.w, b.w);

    out[base]       = lo;
    out[base + HW4] = hi;
}

extern "C" void kernel_launch(void* const* d_in, const int* in_sizes, int n_in,
                              void* d_out, int out_size, void* d_ws, size_t ws_size,
                              hipStream_t stream) {
    const float4* x = (const float4*)d_in[0];
    float4* out = (float4*)d_out;
    int total = out_size / 8;            // pair-vectors: out_size/4 float4s, /2 planes
    int blocks = (total + 255) / 256;
    groupsort_kernel<<<blocks, 256, 0, stream>>>(x, out, total);
}